// Round 12
// baseline (2846.827 us; speedup 1.0000x reference)
//
#include <hip/hip_runtime.h>
#include <stdint.h>

#define T_LEN 128
#define BATCH 128
#define DHID 512
#define H 256
#define NTAGS 60
#define START_TAG 58
#define STOP_TAG 59
#define NEGV -10000.0f

typedef __attribute__((ext_vector_type(4))) float floatx4;
typedef __attribute__((ext_vector_type(2))) float floatx2;
typedef __attribute__((ext_vector_type(8))) int v8i;
typedef unsigned short u16;
typedef unsigned char u8;
typedef unsigned int u32;
typedef unsigned long long u64c;

#define SCALE1 0x7F7F7F7F  // E8M0 = 1.0 in every byte

__device__ __forceinline__ u16 f2bf(float f) {
  union { float f; uint32_t u; } c; c.f = f;
  uint32_t u = c.u;
  u += 0x7FFFu + ((u >> 16) & 1u);
  return (u16)(u >> 16);
}
// HW fp8 (e4m3) conversions
__device__ __forceinline__ floatx4 f8x4tof(u32 v) {
  floatx2 lo = __builtin_amdgcn_cvt_pk_f32_fp8((int)v, false);
  floatx2 hi = __builtin_amdgcn_cvt_pk_f32_fp8((int)v, true);
  floatx4 r;
  r[0] = lo[0]; r[1] = lo[1]; r[2] = hi[0]; r[3] = hi[1];
  return r;
}
__device__ __forceinline__ u8 ftof8(float f) {
  return (u8)(__builtin_amdgcn_cvt_pk_fp8_f32(f, f, 0, false) & 0xff);
}
__device__ __forceinline__ u32 pk4f8(float a, float b, float c, float d) {
  int o = __builtin_amdgcn_cvt_pk_fp8_f32(a, b, 0, false);
  o = __builtin_amdgcn_cvt_pk_fp8_f32(c, d, o, true);
  return (u32)o;
}
__device__ __forceinline__ float sigx(float x) {
  float e = __expf(-x);
  return __builtin_amdgcn_rcpf(1.0f + e);
}
__device__ __forceinline__ float tanhx(float x) {
  float e = __expf(-2.0f * x);
  return 2.0f * __builtin_amdgcn_rcpf(1.0f + e) - 1.0f;
}
__device__ __forceinline__ u32 relu8(u32 a) {
  u32 m = (a & 0x80808080u) >> 7;
  m *= 255u;
  return a & ~m;
}
__device__ __forceinline__ u32 reluadd8(u32 a, u32 b) {
  floatx4 av = f8x4tof(relu8(a));
  floatx4 bv = f8x4tof(relu8(b));
  return pk4f8(av[0] + bv[0], av[1] + bv[1], av[2] + bv[2], av[3] + bv[3]);
}
// 32-byte fragment builders
__device__ __forceinline__ v8i frag_lds(const u8* p) {  // 8-B aligned LDS
  union { long l[4]; v8i v; } u;
  u.l[0] = *(const long*)(p);
  u.l[1] = *(const long*)(p + 8);
  u.l[2] = *(const long*)(p + 16);
  u.l[3] = *(const long*)(p + 24);
  return u.v;
}
__device__ __forceinline__ v8i frag_pair(uint4 a, uint4 b) {
  union { uint4 q[2]; v8i v; } u;
  u.q[0] = a; u.q[1] = b;
  return u.v;
}
#define MFMA128(a, b, c) \
  __builtin_amdgcn_mfma_scale_f32_16x16x128_f8f6f4((a), (b), (c), 0, 0, 0, SCALE1, 0, SCALE1)

// ---------------------------------------------------------------------------
// Pack weights -> fp8: whh [7][2][1024][256], wih [6][2][1024][512], fcw [64][512].
// ---------------------------------------------------------------------------
__global__ void pack_kernel(const float* __restrict__ whh1, const float* __restrict__ whh,
                            const float* __restrict__ wih, const float* __restrict__ fcw,
                            u8* __restrict__ whh_f8, u8* __restrict__ wih_f8,
                            u8* __restrict__ fcw_f8) {
  const int n_whh1 = 2 * 1024 * 256;
  const int n_whh  = 6 * 2 * 1024 * 256;
  const int n_wih  = 6 * 2 * 1024 * 512;
  const int n_fcw  = 64 * 512;
  const int total = n_whh1 + n_whh + n_wih + n_fcw;
  for (int i = blockIdx.x * blockDim.x + threadIdx.x; i < total; i += gridDim.x * blockDim.x) {
    if (i < n_whh1) {
      whh_f8[i] = ftof8(whh1[i]);
    } else if (i < n_whh1 + n_whh) {
      whh_f8[i] = ftof8(whh[i - n_whh1]);
    } else if (i < n_whh1 + n_whh + n_wih) {
      int j = i - n_whh1 - n_whh;
      wih_f8[j] = ftof8(wih[j]);
    } else {
      int j = i - n_whh1 - n_whh - n_wih;
      int row = j >> 9;
      fcw_f8[j] = (row < NTAGS) ? ftof8(fcw[j]) : (u8)0;
    }
  }
}

// ---------------------------------------------------------------------------
// Layer-1 xw (Din=3), fp8, layout xw[bc8][t][col(2048)][16 batches].
// ---------------------------------------------------------------------------
__global__ void xw1_kernel(const float* __restrict__ sent, const float* __restrict__ wih1,
                           const float* __restrict__ b1, u8* __restrict__ xw) {
  int u = blockIdx.x * blockDim.x + threadIdx.x;
  int qq = u & 3;
  int col = (u >> 2) & 2047;
  int t = (u >> 13) & 127;
  int bc = u >> 20;
  const float* w = wih1 + col * 3;
  float w0 = w[0], w1 = w[1], w2 = w[2], bv = b1[col];
  float o[4];
#pragma unroll
  for (int j = 0; j < 4; ++j) {
    int b = bc * 16 + qq * 4 + j;
    const float* x = sent + (t * BATCH + b) * 3;
    o[j] = bv + x[0] * w0 + x[1] * w1 + x[2] * w2;
  }
  *(u32*)(xw + (size_t)u * 4) = pk4f8(o[0], o[1], o[2], o[3]);
}

// ---------------------------------------------------------------------------
// xw GEMM layers 2..7, MX-scaled fp8 MFMA (K=128/instr, scales=1.0).
// A = activations (relu[+residual]) staged in LDS, B = W_ih from global.
// out xw [bc8][t][col][16] fp8.
// ---------------------------------------------------------------------------
__launch_bounds__(256, 4)
__global__ void gemm_xw_kernel(const u8* __restrict__ cur, const u8* __restrict__ prev,
                               const u8* __restrict__ W, const float* __restrict__ bias,
                               u8* __restrict__ xw) {
  __shared__ __align__(16) u8 As[64][136];
  const int nbase = blockIdx.x * 256;
  const int m0 = blockIdx.y * 64;
  const int tid = threadIdx.x;
  const int wv = tid >> 6, ln = tid & 63;
  const int c16 = ln & 15, q = ln >> 4;
  const int ncol0 = nbase + wv * 64;

  floatx4 acc[4][4];
#pragma unroll
  for (int i = 0; i < 4; ++i)
#pragma unroll
    for (int j = 0; j < 4; ++j) { acc[i][j][0] = 0.f; acc[i][j][1] = 0.f; acc[i][j][2] = 0.f; acc[i][j][3] = 0.f; }

  for (int kc = 0; kc < 4; ++kc) {  // K chunks of 128
    // stage 64x128 fp8 activation tile (relu + optional residual): 32 B/thread
    {
      int r = tid >> 2;
      int cb = (tid & 3) * 32;
      size_t g = (size_t)(m0 + r) * DHID + kc * 128 + cb;
      uint4 a0 = *(const uint4*)(cur + g);
      uint4 a1 = *(const uint4*)(cur + g + 16);
      if (prev) {
        uint4 p0 = *(const uint4*)(prev + g);
        uint4 p1 = *(const uint4*)(prev + g + 16);
        a0.x = reluadd8(a0.x, p0.x); a0.y = reluadd8(a0.y, p0.y);
        a0.z = reluadd8(a0.z, p0.z); a0.w = reluadd8(a0.w, p0.w);
        a1.x = reluadd8(a1.x, p1.x); a1.y = reluadd8(a1.y, p1.y);
        a1.z = reluadd8(a1.z, p1.z); a1.w = reluadd8(a1.w, p1.w);
      } else {
        a0.x = relu8(a0.x); a0.y = relu8(a0.y); a0.z = relu8(a0.z); a0.w = relu8(a0.w);
        a1.x = relu8(a1.x); a1.y = relu8(a1.y); a1.z = relu8(a1.z); a1.w = relu8(a1.w);
      }
      u8* dst = &As[r][cb];  // 8-B aligned (136*r + {0,32,64,96})
      ((u64c*)dst)[0] = ((u64c)a0.y << 32) | a0.x;
      ((u64c*)dst)[1] = ((u64c)a0.w << 32) | a0.z;
      ((u64c*)dst)[2] = ((u64c)a1.y << 32) | a1.x;
      ((u64c*)dst)[3] = ((u64c)a1.w << 32) | a1.z;
    }
    __syncthreads();
    {
      v8i bfr[4];
#pragma unroll
      for (int nt = 0; nt < 4; ++nt) {
        const u8* wp = W + (size_t)(ncol0 + nt * 16 + c16) * DHID + kc * 128 + q * 32;
        bfr[nt] = frag_pair(*(const uint4*)wp, *(const uint4*)(wp + 16));
      }
      v8i afr[4];
#pragma unroll
      for (int mt = 0; mt < 4; ++mt)
        afr[mt] = frag_lds(&As[mt * 16 + c16][q * 32]);
#pragma unroll
      for (int nt = 0; nt < 4; ++nt)
#pragma unroll
        for (int mt = 0; mt < 4; ++mt)
          acc[nt][mt] = MFMA128(afr[mt], bfr[nt], acc[nt][mt]);
    }
    __syncthreads();
  }
  const int t = m0 >> 7;
  const int bc0 = (m0 & 127) >> 4;
#pragma unroll
  for (int nt = 0; nt < 4; ++nt) {
    int col = ncol0 + nt * 16 + c16;
    float bv = bias[col];
#pragma unroll
    for (int mt = 0; mt < 4; ++mt) {
      u32 o = pk4f8(acc[nt][mt][0] + bv, acc[nt][mt][1] + bv,
                    acc[nt][mt][2] + bv, acc[nt][mt][3] + bv);
      *(u32*)(xw + (((size_t)(bc0 + mt) * T_LEN + t) * 2048 + col) * 16 + q * 4) = o;
    }
  }
}

// ---------------------------------------------------------------------------
// LSTM scan. Grid: 16 (dir*8+bc), block 512 (8 waves, 2/SIMD).
// A = h (M=batch=c16), B = W (N=gate-col). MX-scaled K=128 MFMA (2/gate-chain).
// Gates i,f: W LDS-resident (264-stride, conflict-free).
// Gates g,o: W streamed from L2 per step via explicit uint4 loads (issued
// early, consumed same iteration -> no loop-carried-residency problem).
// h fp8 double-buffered LDS; one barrier/step; obuf fp8 straight copy.
// ---------------------------------------------------------------------------
__launch_bounds__(512, 1)
__global__ void scan_kernel(const u8* __restrict__ whh, const u8* __restrict__ xw,
                            const float* __restrict__ h0, const float* __restrict__ c0,
                            u8* __restrict__ obuf) {
  __shared__ __align__(16) u8 Wl[512][264];     // 135168 B (gates i,f)
  __shared__ __align__(16) u8 hbuf[2][16][264]; //   8448 B (total 143616)
  const int bc  = blockIdx.x & 7;
  const int dir = blockIdx.x >> 3;
  const int b0  = bc * 16;
  const int tid = threadIdx.x;
  const int ln = tid & 63;
  const int wv = tid >> 6;
  const int c16 = ln & 15, q = ln >> 4;
  const int col0 = wv * 32;  // wave's 32 h-cols

  // --- Wl fill: gates 0,1 (i,f), row tid = g*256+col, contiguous K ---
  {
    const u8* wr = whh + ((size_t)dir * 1024 + tid) * 256;
#pragma unroll
    for (int kk = 0; kk < 256; kk += 8)
      *(u64c*)(&Wl[tid][kk]) = *(const u64c*)(wr + kk);
  }
  // --- h0 -> hbuf[0] (fp8; rows = batch 0..15) ---
  {
    int row = tid >> 5, cc = (tid & 31) * 8;
    const float* hr = h0 + ((size_t)dir * BATCH + b0 + row) * H + cc;
    *(u32*)(&hbuf[0][row][cc])     = pk4f8(hr[0], hr[1], hr[2], hr[3]);
    *(u32*)(&hbuf[0][row][cc + 4]) = pk4f8(hr[4], hr[5], hr[6], hr[7]);
  }
  // --- c state: batch = q*4+r, col = col0+st*16+c16 ---
  float creg[2][4];
#pragma unroll
  for (int st = 0; st < 2; ++st)
#pragma unroll
    for (int r = 0; r < 4; ++r)
      creg[st][r] = c0[((size_t)dir * BATCH + b0 + q * 4 + r) * H + col0 + st * 16 + c16];
  __syncthreads();

  // g/o W global row bases (per-lane constant)
  const u8* wgo[2][2];  // [g2][st]
#pragma unroll
  for (int g2 = 0; g2 < 2; ++g2)
#pragma unroll
    for (int st = 0; st < 2; ++st)
      wgo[g2][st] = whh + ((size_t)dir * 1024 + (g2 + 2) * 256 + col0 + st * 16 + c16) * 256 + q * 32;

  // xw addressing
  const u8* xwt = xw + ((size_t)bc * T_LEN + (dir ? T_LEN - 1 : 0)) * 2048 * 16;
  const ptrdiff_t xstep = (dir ? -1 : 1) * (ptrdiff_t)(2048 * 16);
  int xoff[4][2];
#pragma unroll
  for (int g = 0; g < 4; ++g)
#pragma unroll
    for (int st = 0; st < 2; ++st)
      xoff[g][st] = (dir * 1024 + g * 256 + col0 + st * 16 + c16) * 16 + q * 4;

  u8* obt = obuf + ((size_t)(dir ? T_LEN - 1 : 0) * BATCH) * DHID;
  const ptrdiff_t ostep = (dir ? -1 : 1) * (ptrdiff_t)(BATCH * DHID);

  // prefetch s=0 xw
  u32 xwn[4][2];
#pragma unroll
  for (int g = 0; g < 4; ++g)
#pragma unroll
    for (int st = 0; st < 2; ++st)
      xwn[g][st] = *(const u32*)(xwt + xoff[g][st]);

  for (int s = 0; s < T_LEN; ++s) {
    const int p = s & 1, pn = p ^ 1;

    // 1) acc init from xw (registers)
    floatx4 acc[4][2];
#pragma unroll
    for (int g = 0; g < 4; ++g)
#pragma unroll
      for (int st = 0; st < 2; ++st)
        acc[g][st] = f8x4tof(xwn[g][st]);

    // 2) issue g/o W streams (16 uint4 loads; drain under i/f MFMA phase)
    uint4 wgl[2][2][2][2];  // [g2][st][kc][half]
#pragma unroll
    for (int g2 = 0; g2 < 2; ++g2)
#pragma unroll
      for (int st = 0; st < 2; ++st)
#pragma unroll
        for (int kc = 0; kc < 2; ++kc) {
          const u8* p4 = wgo[g2][st] + kc * 128;
          wgl[g2][st][kc][0] = *(const uint4*)p4;
          wgl[g2][st][kc][1] = *(const uint4*)(p4 + 16);
        }

    // 3) prefetch next step's xw
    if (s + 1 < T_LEN) {
      const u8* xn = xwt + xstep;
#pragma unroll
      for (int g = 0; g < 4; ++g)
#pragma unroll
        for (int st = 0; st < 2; ++st)
          xwn[g][st] = *(const u32*)(xn + xoff[g][st]);
    }

    // 4) h A-frags (2 K-chunks of 128)
    v8i hfr[2];
#pragma unroll
    for (int kc = 0; kc < 2; ++kc)
      hfr[kc] = frag_lds(&hbuf[p][c16][kc * 128 + q * 32]);

    // 5) gates i,f: B-frags from LDS Wl
#pragma unroll
    for (int g01 = 0; g01 < 2; ++g01)
#pragma unroll
      for (int st = 0; st < 2; ++st) {
        const u8* wr = &Wl[g01 * 256 + col0 + st * 16 + c16][0];
#pragma unroll
        for (int kc = 0; kc < 2; ++kc) {
          v8i b = frag_lds(wr + kc * 128 + q * 32);
          acc[g01][st] = MFMA128(hfr[kc], b, acc[g01][st]);
        }
      }
    // 6) gates g,o: B-frags from the streamed registers
#pragma unroll
    for (int g2 = 0; g2 < 2; ++g2)
#pragma unroll
      for (int st = 0; st < 2; ++st)
#pragma unroll
        for (int kc = 0; kc < 2; ++kc)
          acc[g2 + 2][st] = MFMA128(hfr[kc], frag_pair(wgl[g2][st][kc][0], wgl[g2][st][kc][1]),
                                    acc[g2 + 2][st]);

    // 7) gates -> h' (batch = q*4+r, col = col0+st*16+c16)
#pragma unroll
    for (int st = 0; st < 2; ++st)
#pragma unroll
      for (int r = 0; r < 4; ++r) {
        float ig = sigx(acc[0][st][r]);
        float fg = sigx(acc[1][st][r]);
        float gg = tanhx(acc[2][st][r]);
        float og = sigx(acc[3][st][r]);
        float cn = fg * creg[st][r] + ig * gg;
        creg[st][r] = cn;
        hbuf[pn][q * 4 + r][col0 + st * 16 + c16] = ftof8(og * tanhx(cn));
      }
    __syncthreads();

    // 8) obuf copy (fp8, 8B/thread, coalesced)
    {
      int row = tid >> 5, cc = (tid & 31) * 8;
      u64c v = *(const u64c*)(&hbuf[pn][row][cc]);
      *(u64c*)(obt + ((size_t)(b0 + row)) * DHID + dir * H + cc) = v;
    }
    xwt += xstep;
    obt += ostep;
  }
}

// ---------------------------------------------------------------------------
// FC: feats[16384][64] = out7(fp8)[16384][512] @ fcw^T + fc_b  (fp8 MFMA)
// ---------------------------------------------------------------------------
__launch_bounds__(256, 4)
__global__ void fc_kernel(const u8* __restrict__ A, const u8* __restrict__ W,
                          const float* __restrict__ fb, float* __restrict__ feats) {
  const int tid = threadIdx.x, wv = tid >> 6, ln = tid & 63;
  const int c16 = ln & 15, q = ln >> 4;
  const int m0 = blockIdx.x * 64 + wv * 16;
  floatx4 acc[4];
#pragma unroll
  for (int i = 0; i < 4; ++i) { acc[i][0] = 0.f; acc[i][1] = 0.f; acc[i][2] = 0.f; acc[i][3] = 0.f; }
#pragma unroll
  for (int kt = 0; kt < 16; ++kt) {
    long a = *(const long*)(A + (size_t)(m0 + c16) * DHID + kt * 32 + q * 8);
#pragma unroll
    for (int nt = 0; nt < 4; ++nt) {
      long b = *(const long*)(W + (size_t)(nt * 16 + c16) * DHID + kt * 32 + q * 8);
      acc[nt] = __builtin_amdgcn_mfma_f32_16x16x32_fp8_fp8(a, b, acc[nt], 0, 0, 0);
    }
  }
#pragma unroll
  for (int nt = 0; nt < 4; ++nt) {
    int n = nt * 16 + c16;
    if (n < NTAGS) {
      float bv = fb[n];
#pragma unroll
      for (int r = 0; r < 4; ++r)
        feats[(size_t)(m0 + q * 4 + r) * 64 + n] = acc[nt][r] + bv;
    }
  }
}

// ---------------------------------------------------------------------------
// CRF: one wave per batch item.
// ---------------------------------------------------------------------------
__launch_bounds__(64, 1)
__global__ void crf_kernel(const float* __restrict__ feats, const float* __restrict__ trans,
                           const int* __restrict__ tags, float* __restrict__ out) {
  __shared__ float Tl[60][65];
  __shared__ float abuf[2][64];
  const int b = blockIdx.x;
  const int ln = threadIdx.x;
  for (int i = ln; i < 3600; i += 64) Tl[i / 60][i % 60] = trans[i];
  __syncthreads();

  float gsc = 0.f;
  for (int t = ln; t < T_LEN; t += 64) {
    int tg = tags[t * BATCH + b];
    int pv = (t == 0) ? START_TAG : tags[(t - 1) * BATCH + b];
    gsc += Tl[tg][pv] + feats[(size_t)(t * BATCH + b) * 64 + tg];
  }
#pragma unroll
  for (int off = 32; off > 0; off >>= 1) gsc += __shfl_down(gsc, off);
  if (ln == 0) gsc += Tl[STOP_TAG][tags[(T_LEN - 1) * BATCH + b]];

  abuf[0][ln] = (ln == START_TAG) ? 0.f : NEGV;
  __syncthreads();
  const float* Trow = Tl[ln < NTAGS ? ln : 0];
  const int myk = (ln < NTAGS) ? ln : 0;
  for (int t = 0; t < T_LEN; ++t) {
    const int cb = t & 1, nb2 = cb ^ 1;
    float m = -1e30f;
    for (int p = 0; p < NTAGS; ++p) m = fmaxf(m, abuf[cb][p] + Trow[p]);
    float ssum = 0.f;
    for (int p = 0; p < NTAGS; ++p) ssum += __expf(abuf[cb][p] + Trow[p] - m);
    float nv = m + __logf(ssum) + feats[(size_t)(t * BATCH + b) * 64 + myk];
    abuf[nb2][ln] = (ln < NTAGS) ? nv : NEGV;
    __syncthreads();
  }

  float v = (ln < NTAGS) ? (abuf[T_LEN & 1][ln] + Tl[STOP_TAG][ln]) : -1e30f;
  float mm = v;
#pragma unroll
  for (int off = 32; off > 0; off >>= 1) mm = fmaxf(mm, __shfl_down(mm, off));
  mm = __shfl(mm, 0);
  float es = __expf(v - mm);
#pragma unroll
  for (int off = 32; off > 0; off >>= 1) es += __shfl_down(es, off);
  if (ln == 0) out[b] = mm + __logf(es) - gsc;
}

// ---------------------------------------------------------------------------
extern "C" void kernel_launch(void* const* d_in, const int* in_sizes, int n_in,
                              void* d_out, int out_size, void* d_ws, size_t ws_size,
                              hipStream_t stream) {
  (void)in_sizes; (void)n_in; (void)out_size; (void)ws_size;
  const float* sent  = (const float*)d_in[0];
  const int*   tags  = (const int*)d_in[1];
  const float* wih1  = (const float*)d_in[2];
  const float* whh1  = (const float*)d_in[3];
  const float* b1    = (const float*)d_in[4];
  const float* wih   = (const float*)d_in[5];
  const float* whh   = (const float*)d_in[6];
  const float* bias  = (const float*)d_in[7];
  const float* fcw   = (const float*)d_in[8];
  const float* fcb   = (const float*)d_in[9];
  const float* h0    = (const float*)d_in[10];
  const float* c0    = (const float*)d_in[11];
  const float* trans = (const float*)d_in[12];
  float* out = (float*)d_out;

  char* ws = (char*)d_ws;
  size_t off = 0;
  auto alloc = [&](size_t bytes) -> void* {
    void* p = ws + off;
    off = (off + bytes + 255) & ~(size_t)255;
    return p;
  };
  u8* whh_f8 = (u8*)alloc((size_t)7 * 2 * 1024 * 256);
  u8* wih_f8 = (u8*)alloc((size_t)6 * 2 * 1024 * 512);
  u8* fcw_f8 = (u8*)alloc((size_t)64 * 512);
  u8* xw     = (u8*)alloc((size_t)16384 * 2048);
  u8* ob[3];
  for (int i = 0; i < 3; ++i) ob[i] = (u8*)alloc((size_t)16384 * 512);
  float* feats = (float*)alloc((size_t)16384 * 64 * 4);

  hipLaunchKernelGGL(pack_kernel, dim3(4096), dim3(256), 0, stream,
                     whh1, whh, wih, fcw, whh_f8, wih_f8, fcw_f8);
  hipLaunchKernelGGL(xw1_kernel, dim3(32768), dim3(256), 0, stream, sent, wih1, b1, xw);
  hipLaunchKernelGGL(scan_kernel, dim3(16), dim3(512), 0, stream,
                     whh_f8, xw, h0, c0, ob[0]);
  for (int L = 1; L < 7; ++L) {
    const u8* curb = ob[(L - 1) % 3];
    const u8* prevb = (L >= 2) ? ob[(L - 2) % 3] : nullptr;
    hipLaunchKernelGGL(gemm_xw_kernel, dim3(8, 256), dim3(256), 0, stream,
                       curb, prevb, wih_f8 + (size_t)(L - 1) * 2 * 1024 * 512,
                       bias + (size_t)(L - 1) * 2048, xw);
    hipLaunchKernelGGL(scan_kernel, dim3(16), dim3(512), 0, stream,
                       whh_f8 + (size_t)L * 2 * 1024 * 256, xw,
                       h0 + (size_t)L * 2 * 128 * 256, c0 + (size_t)L * 2 * 128 * 256,
                       ob[L % 3]);
  }
  hipLaunchKernelGGL(fc_kernel, dim3(256), dim3(256), 0, stream, ob[0], fcw_f8, fcb, feats);
  hipLaunchKernelGGL(crf_kernel, dim3(128), dim3(64), 0, stream, feats, trans, tags, out);
}

// Round 13
// 2518.547 us; speedup vs baseline: 1.1303x; 1.1303x over previous
//
#include <hip/hip_runtime.h>
#include <stdint.h>

#define T_LEN 128
#define BATCH 128
#define DHID 512
#define H 256
#define NTAGS 60
#define START_TAG 58
#define STOP_TAG 59
#define NEGV -10000.0f

typedef __attribute__((ext_vector_type(4))) float floatx4;
typedef __attribute__((ext_vector_type(2))) float floatx2;
typedef __attribute__((ext_vector_type(8))) int v8i;
typedef unsigned short u16;
typedef unsigned char u8;
typedef unsigned int u32;
typedef unsigned long long u64c;

#define SCALE1 0x7F7F7F7F  // E8M0 = 1.0 in every byte

__device__ __forceinline__ u16 f2bf(float f) {
  union { float f; uint32_t u; } c; c.f = f;
  uint32_t u = c.u;
  u += 0x7FFFu + ((u >> 16) & 1u);
  return (u16)(u >> 16);
}
// HW fp8 (e4m3) conversions
__device__ __forceinline__ floatx4 f8x4tof(u32 v) {
  floatx2 lo = __builtin_amdgcn_cvt_pk_f32_fp8((int)v, false);
  floatx2 hi = __builtin_amdgcn_cvt_pk_f32_fp8((int)v, true);
  floatx4 r;
  r[0] = lo[0]; r[1] = lo[1]; r[2] = hi[0]; r[3] = hi[1];
  return r;
}
__device__ __forceinline__ u8 ftof8(float f) {
  return (u8)(__builtin_amdgcn_cvt_pk_fp8_f32(f, f, 0, false) & 0xff);
}
__device__ __forceinline__ u32 pk4f8(float a, float b, float c, float d) {
  int o = __builtin_amdgcn_cvt_pk_fp8_f32(a, b, 0, false);
  o = __builtin_amdgcn_cvt_pk_fp8_f32(c, d, o, true);
  return (u32)o;
}
__device__ __forceinline__ float sigx(float x) {
  float e = __expf(-x);
  return __builtin_amdgcn_rcpf(1.0f + e);
}
__device__ __forceinline__ float tanhx(float x) {
  float e = __expf(-2.0f * x);
  return 2.0f * __builtin_amdgcn_rcpf(1.0f + e) - 1.0f;
}
__device__ __forceinline__ u32 relu8(u32 a) {
  u32 m = (a & 0x80808080u) >> 7;
  m *= 255u;
  return a & ~m;
}
__device__ __forceinline__ u32 reluadd8(u32 a, u32 b) {
  floatx4 av = f8x4tof(relu8(a));
  floatx4 bv = f8x4tof(relu8(b));
  return pk4f8(av[0] + bv[0], av[1] + bv[1], av[2] + bv[2], av[3] + bv[3]);
}
// 32-byte fragment builders (scan only)
__device__ __forceinline__ v8i frag_lds(const u8* p) {  // 8-B aligned LDS
  union { long l[4]; v8i v; } u;
  u.l[0] = *(const long*)(p);
  u.l[1] = *(const long*)(p + 8);
  u.l[2] = *(const long*)(p + 16);
  u.l[3] = *(const long*)(p + 24);
  return u.v;
}
__device__ __forceinline__ v8i frag_pair(uint4 a, uint4 b) {
  union { uint4 q[2]; v8i v; } u;
  u.q[0] = a; u.q[1] = b;
  return u.v;
}
#define MFMA128(a, b, c) \
  __builtin_amdgcn_mfma_scale_f32_16x16x128_f8f6f4((a), (b), (c), 0, 0, 0, SCALE1, 0, SCALE1)

// ---------------------------------------------------------------------------
// Pack weights -> fp8: whh [7][2][1024][256], wih [6][2][1024][512], fcw [64][512].
// ---------------------------------------------------------------------------
__global__ void pack_kernel(const float* __restrict__ whh1, const float* __restrict__ whh,
                            const float* __restrict__ wih, const float* __restrict__ fcw,
                            u8* __restrict__ whh_f8, u8* __restrict__ wih_f8,
                            u8* __restrict__ fcw_f8) {
  const int n_whh1 = 2 * 1024 * 256;
  const int n_whh  = 6 * 2 * 1024 * 256;
  const int n_wih  = 6 * 2 * 1024 * 512;
  const int n_fcw  = 64 * 512;
  const int total = n_whh1 + n_whh + n_wih + n_fcw;
  for (int i = blockIdx.x * blockDim.x + threadIdx.x; i < total; i += gridDim.x * blockDim.x) {
    if (i < n_whh1) {
      whh_f8[i] = ftof8(whh1[i]);
    } else if (i < n_whh1 + n_whh) {
      whh_f8[i] = ftof8(whh[i - n_whh1]);
    } else if (i < n_whh1 + n_whh + n_wih) {
      int j = i - n_whh1 - n_whh;
      wih_f8[j] = ftof8(wih[j]);
    } else {
      int j = i - n_whh1 - n_whh - n_wih;
      int row = j >> 9;
      fcw_f8[j] = (row < NTAGS) ? ftof8(fcw[j]) : (u8)0;
    }
  }
}

// ---------------------------------------------------------------------------
// Layer-1 xw (Din=3), fp8, layout xw[bc8][t][col(2048)][16 batches].
// ---------------------------------------------------------------------------
__global__ void xw1_kernel(const float* __restrict__ sent, const float* __restrict__ wih1,
                           const float* __restrict__ b1, u8* __restrict__ xw) {
  int u = blockIdx.x * blockDim.x + threadIdx.x;
  int qq = u & 3;
  int col = (u >> 2) & 2047;
  int t = (u >> 13) & 127;
  int bc = u >> 20;
  const float* w = wih1 + col * 3;
  float w0 = w[0], w1 = w[1], w2 = w[2], bv = b1[col];
  float o[4];
#pragma unroll
  for (int j = 0; j < 4; ++j) {
    int b = bc * 16 + qq * 4 + j;
    const float* x = sent + (t * BATCH + b) * 3;
    o[j] = bv + x[0] * w0 + x[1] * w1 + x[2] * w2;
  }
  *(u32*)(xw + (size_t)u * 4) = pk4f8(o[0], o[1], o[2], o[3]);
}

// ---------------------------------------------------------------------------
// xw GEMM layers 2..7 (R10 version: plain fp8 K=32 MFMA — measured fastest).
// A = activations (relu[+residual]) staged in LDS, B = W_ih from global.
// out xw [bc8][t][col][16] fp8.
// ---------------------------------------------------------------------------
__launch_bounds__(256, 4)
__global__ void gemm_xw_kernel(const u8* __restrict__ cur, const u8* __restrict__ prev,
                               const u8* __restrict__ W, const float* __restrict__ bias,
                               u8* __restrict__ xw) {
  __shared__ __align__(16) u8 As[64][72];
  const int nbase = blockIdx.x * 256;
  const int m0 = blockIdx.y * 64;
  const int tid = threadIdx.x;
  const int wv = tid >> 6, ln = tid & 63;
  const int c16 = ln & 15, q = ln >> 4;
  const int ncol0 = nbase + wv * 64;

  floatx4 acc[4][4];
#pragma unroll
  for (int i = 0; i < 4; ++i)
#pragma unroll
    for (int j = 0; j < 4; ++j) { acc[i][j][0] = 0.f; acc[i][j][1] = 0.f; acc[i][j][2] = 0.f; acc[i][j][3] = 0.f; }

  for (int kc = 0; kc < 8; ++kc) {
    {
      int r = tid >> 2;
      int cb = (tid & 3) * 16;
      size_t g = (size_t)(m0 + r) * DHID + kc * 64 + cb;
      uint4 a4 = *(const uint4*)(cur + g);
      if (prev) {
        uint4 p4 = *(const uint4*)(prev + g);
        a4.x = reluadd8(a4.x, p4.x); a4.y = reluadd8(a4.y, p4.y);
        a4.z = reluadd8(a4.z, p4.z); a4.w = reluadd8(a4.w, p4.w);
      } else {
        a4.x = relu8(a4.x); a4.y = relu8(a4.y);
        a4.z = relu8(a4.z); a4.w = relu8(a4.w);
      }
      u64c lo = ((u64c)a4.y << 32) | a4.x;
      u64c hi = ((u64c)a4.w << 32) | a4.z;
      *(u64c*)(&As[r][cb]) = lo;
      *(u64c*)(&As[r][cb + 8]) = hi;
    }
    __syncthreads();
#pragma unroll
    for (int kt = 0; kt < 2; ++kt) {
      int kg = kc * 64 + kt * 32 + q * 8;
      long bfr[4];
#pragma unroll
      for (int nt = 0; nt < 4; ++nt)
        bfr[nt] = *(const long*)(W + (size_t)(ncol0 + nt * 16 + c16) * DHID + kg);
      long afr[4];
#pragma unroll
      for (int mt = 0; mt < 4; ++mt)
        afr[mt] = *(const long*)(&As[mt * 16 + c16][kt * 32 + q * 8]);
#pragma unroll
      for (int nt = 0; nt < 4; ++nt)
#pragma unroll
        for (int mt = 0; mt < 4; ++mt)
          acc[nt][mt] = __builtin_amdgcn_mfma_f32_16x16x32_fp8_fp8(afr[mt], bfr[nt], acc[nt][mt], 0, 0, 0);
    }
    __syncthreads();
  }
  const int t = m0 >> 7;
  const int bc0 = (m0 & 127) >> 4;
#pragma unroll
  for (int nt = 0; nt < 4; ++nt) {
    int col = ncol0 + nt * 16 + c16;
    float bv = bias[col];
#pragma unroll
    for (int mt = 0; mt < 4; ++mt) {
      u32 o = pk4f8(acc[nt][mt][0] + bv, acc[nt][mt][1] + bv,
                    acc[nt][mt][2] + bv, acc[nt][mt][3] + bv);
      *(u32*)(xw + (((size_t)(bc0 + mt) * T_LEN + t) * 2048 + col) * 16 + q * 4) = o;
    }
  }
}

// ---------------------------------------------------------------------------
// LSTM scan (R12 version — best measured, 260 µs). Grid: 16 (dir*8+bc),
// block 512 (8 waves). A = h (M=batch=c16), B = W. MX-scaled K=128 MFMA.
// Gates i,f: W LDS-resident (264-stride, conflict-free).
// Gates g,o: W streamed from L2 per step (consumed same iteration).
// h fp8 double-buffered LDS; one barrier/step; obuf fp8 straight copy.
// ---------------------------------------------------------------------------
__launch_bounds__(512, 1)
__global__ void scan_kernel(const u8* __restrict__ whh, const u8* __restrict__ xw,
                            const float* __restrict__ h0, const float* __restrict__ c0,
                            u8* __restrict__ obuf) {
  __shared__ __align__(16) u8 Wl[512][264];     // 135168 B (gates i,f)
  __shared__ __align__(16) u8 hbuf[2][16][264]; //   8448 B (total 143616)
  const int bc  = blockIdx.x & 7;
  const int dir = blockIdx.x >> 3;
  const int b0  = bc * 16;
  const int tid = threadIdx.x;
  const int ln = tid & 63;
  const int wv = tid >> 6;
  const int c16 = ln & 15, q = ln >> 4;
  const int col0 = wv * 32;  // wave's 32 h-cols

  // --- Wl fill: gates 0,1 (i,f), row tid = g*256+col, contiguous K ---
  {
    const u8* wr = whh + ((size_t)dir * 1024 + tid) * 256;
#pragma unroll
    for (int kk = 0; kk < 256; kk += 8)
      *(u64c*)(&Wl[tid][kk]) = *(const u64c*)(wr + kk);
  }
  // --- h0 -> hbuf[0] (fp8; rows = batch 0..15) ---
  {
    int row = tid >> 5, cc = (tid & 31) * 8;
    const float* hr = h0 + ((size_t)dir * BATCH + b0 + row) * H + cc;
    *(u32*)(&hbuf[0][row][cc])     = pk4f8(hr[0], hr[1], hr[2], hr[3]);
    *(u32*)(&hbuf[0][row][cc + 4]) = pk4f8(hr[4], hr[5], hr[6], hr[7]);
  }
  // --- c state: batch = q*4+r, col = col0+st*16+c16 ---
  float creg[2][4];
#pragma unroll
  for (int st = 0; st < 2; ++st)
#pragma unroll
    for (int r = 0; r < 4; ++r)
      creg[st][r] = c0[((size_t)dir * BATCH + b0 + q * 4 + r) * H + col0 + st * 16 + c16];
  __syncthreads();

  // g/o W global row bases (per-lane constant)
  const u8* wgo[2][2];  // [g2][st]
#pragma unroll
  for (int g2 = 0; g2 < 2; ++g2)
#pragma unroll
    for (int st = 0; st < 2; ++st)
      wgo[g2][st] = whh + ((size_t)dir * 1024 + (g2 + 2) * 256 + col0 + st * 16 + c16) * 256 + q * 32;

  // xw addressing
  const u8* xwt = xw + ((size_t)bc * T_LEN + (dir ? T_LEN - 1 : 0)) * 2048 * 16;
  const ptrdiff_t xstep = (dir ? -1 : 1) * (ptrdiff_t)(2048 * 16);
  int xoff[4][2];
#pragma unroll
  for (int g = 0; g < 4; ++g)
#pragma unroll
    for (int st = 0; st < 2; ++st)
      xoff[g][st] = (dir * 1024 + g * 256 + col0 + st * 16 + c16) * 16 + q * 4;

  u8* obt = obuf + ((size_t)(dir ? T_LEN - 1 : 0) * BATCH) * DHID;
  const ptrdiff_t ostep = (dir ? -1 : 1) * (ptrdiff_t)(BATCH * DHID);

  // prefetch s=0 xw
  u32 xwn[4][2];
#pragma unroll
  for (int g = 0; g < 4; ++g)
#pragma unroll
    for (int st = 0; st < 2; ++st)
      xwn[g][st] = *(const u32*)(xwt + xoff[g][st]);

  for (int s = 0; s < T_LEN; ++s) {
    const int p = s & 1, pn = p ^ 1;

    // 1) acc init from xw (registers)
    floatx4 acc[4][2];
#pragma unroll
    for (int g = 0; g < 4; ++g)
#pragma unroll
      for (int st = 0; st < 2; ++st)
        acc[g][st] = f8x4tof(xwn[g][st]);

    // 2) issue g/o W streams (16 uint4 loads; drain under i/f MFMA phase)
    uint4 wgl[2][2][2][2];  // [g2][st][kc][half]
#pragma unroll
    for (int g2 = 0; g2 < 2; ++g2)
#pragma unroll
      for (int st = 0; st < 2; ++st)
#pragma unroll
        for (int kc = 0; kc < 2; ++kc) {
          const u8* p4 = wgo[g2][st] + kc * 128;
          wgl[g2][st][kc][0] = *(const uint4*)p4;
          wgl[g2][st][kc][1] = *(const uint4*)(p4 + 16);
        }

    // 3) prefetch next step's xw
    if (s + 1 < T_LEN) {
      const u8* xn = xwt + xstep;
#pragma unroll
      for (int g = 0; g < 4; ++g)
#pragma unroll
        for (int st = 0; st < 2; ++st)
          xwn[g][st] = *(const u32*)(xn + xoff[g][st]);
    }

    // 4) h A-frags (2 K-chunks of 128)
    v8i hfr[2];
#pragma unroll
    for (int kc = 0; kc < 2; ++kc)
      hfr[kc] = frag_lds(&hbuf[p][c16][kc * 128 + q * 32]);

    // 5) gates i,f: B-frags from LDS Wl
#pragma unroll
    for (int g01 = 0; g01 < 2; ++g01)
#pragma unroll
      for (int st = 0; st < 2; ++st) {
        const u8* wr = &Wl[g01 * 256 + col0 + st * 16 + c16][0];
#pragma unroll
        for (int kc = 0; kc < 2; ++kc) {
          v8i b = frag_lds(wr + kc * 128 + q * 32);
          acc[g01][st] = MFMA128(hfr[kc], b, acc[g01][st]);
        }
      }
    // 6) gates g,o: B-frags from the streamed registers
#pragma unroll
    for (int g2 = 0; g2 < 2; ++g2)
#pragma unroll
      for (int st = 0; st < 2; ++st)
#pragma unroll
        for (int kc = 0; kc < 2; ++kc)
          acc[g2 + 2][st] = MFMA128(hfr[kc], frag_pair(wgl[g2][st][kc][0], wgl[g2][st][kc][1]),
                                    acc[g2 + 2][st]);

    // 7) gates -> h' (batch = q*4+r, col = col0+st*16+c16)
#pragma unroll
    for (int st = 0; st < 2; ++st)
#pragma unroll
      for (int r = 0; r < 4; ++r) {
        float ig = sigx(acc[0][st][r]);
        float fg = sigx(acc[1][st][r]);
        float gg = tanhx(acc[2][st][r]);
        float og = sigx(acc[3][st][r]);
        float cn = fg * creg[st][r] + ig * gg;
        creg[st][r] = cn;
        hbuf[pn][q * 4 + r][col0 + st * 16 + c16] = ftof8(og * tanhx(cn));
      }
    __syncthreads();

    // 8) obuf copy (fp8, 8B/thread, coalesced)
    {
      int row = tid >> 5, cc = (tid & 31) * 8;
      u64c v = *(const u64c*)(&hbuf[pn][row][cc]);
      *(u64c*)(obt + ((size_t)(b0 + row)) * DHID + dir * H + cc) = v;
    }
    xwt += xstep;
    obt += ostep;
  }
}

// ---------------------------------------------------------------------------
// FC: feats[16384][64] = out7(fp8)[16384][512] @ fcw^T + fc_b  (fp8 MFMA)
// ---------------------------------------------------------------------------
__launch_bounds__(256, 4)
__global__ void fc_kernel(const u8* __restrict__ A, const u8* __restrict__ W,
                          const float* __restrict__ fb, float* __restrict__ feats) {
  const int tid = threadIdx.x, wv = tid >> 6, ln = tid & 63;
  const int c16 = ln & 15, q = ln >> 4;
  const int m0 = blockIdx.x * 64 + wv * 16;
  floatx4 acc[4];
#pragma unroll
  for (int i = 0; i < 4; ++i) { acc[i][0] = 0.f; acc[i][1] = 0.f; acc[i][2] = 0.f; acc[i][3] = 0.f; }
#pragma unroll
  for (int kt = 0; kt < 16; ++kt) {
    long a = *(const long*)(A + (size_t)(m0 + c16) * DHID + kt * 32 + q * 8);
#pragma unroll
    for (int nt = 0; nt < 4; ++nt) {
      long b = *(const long*)(W + (size_t)(nt * 16 + c16) * DHID + kt * 32 + q * 8);
      acc[nt] = __builtin_amdgcn_mfma_f32_16x16x32_fp8_fp8(a, b, acc[nt], 0, 0, 0);
    }
  }
#pragma unroll
  for (int nt = 0; nt < 4; ++nt) {
    int n = nt * 16 + c16;
    if (n < NTAGS) {
      float bv = fb[n];
#pragma unroll
      for (int r = 0; r < 4; ++r)
        feats[(size_t)(m0 + q * 4 + r) * 64 + n] = acc[nt][r] + bv;
    }
  }
}

// ---------------------------------------------------------------------------
// CRF: one wave per batch item.
// ---------------------------------------------------------------------------
__launch_bounds__(64, 1)
__global__ void crf_kernel(const float* __restrict__ feats, const float* __restrict__ trans,
                           const int* __restrict__ tags, float* __restrict__ out) {
  __shared__ float Tl[60][65];
  __shared__ float abuf[2][64];
  const int b = blockIdx.x;
  const int ln = threadIdx.x;
  for (int i = ln; i < 3600; i += 64) Tl[i / 60][i % 60] = trans[i];
  __syncthreads();

  float gsc = 0.f;
  for (int t = ln; t < T_LEN; t += 64) {
    int tg = tags[t * BATCH + b];
    int pv = (t == 0) ? START_TAG : tags[(t - 1) * BATCH + b];
    gsc += Tl[tg][pv] + feats[(size_t)(t * BATCH + b) * 64 + tg];
  }
#pragma unroll
  for (int off = 32; off > 0; off >>= 1) gsc += __shfl_down(gsc, off);
  if (ln == 0) gsc += Tl[STOP_TAG][tags[(T_LEN - 1) * BATCH + b]];

  abuf[0][ln] = (ln == START_TAG) ? 0.f : NEGV;
  __syncthreads();
  const float* Trow = Tl[ln < NTAGS ? ln : 0];
  const int myk = (ln < NTAGS) ? ln : 0;
  for (int t = 0; t < T_LEN; ++t) {
    const int cb = t & 1, nb2 = cb ^ 1;
    float m = -1e30f;
    for (int p = 0; p < NTAGS; ++p) m = fmaxf(m, abuf[cb][p] + Trow[p]);
    float ssum = 0.f;
    for (int p = 0; p < NTAGS; ++p) ssum += __expf(abuf[cb][p] + Trow[p] - m);
    float nv = m + __logf(ssum) + feats[(size_t)(t * BATCH + b) * 64 + myk];
    abuf[nb2][ln] = (ln < NTAGS) ? nv : NEGV;
    __syncthreads();
  }

  float v = (ln < NTAGS) ? (abuf[T_LEN & 1][ln] + Tl[STOP_TAG][ln]) : -1e30f;
  float mm = v;
#pragma unroll
  for (int off = 32; off > 0; off >>= 1) mm = fmaxf(mm, __shfl_down(mm, off));
  mm = __shfl(mm, 0);
  float es = __expf(v - mm);
#pragma unroll
  for (int off = 32; off > 0; off >>= 1) es += __shfl_down(es, off);
  if (ln == 0) out[b] = mm + __logf(es) - gsc;
}

// ---------------------------------------------------------------------------
extern "C" void kernel_launch(void* const* d_in, const int* in_sizes, int n_in,
                              void* d_out, int out_size, void* d_ws, size_t ws_size,
                              hipStream_t stream) {
  (void)in_sizes; (void)n_in; (void)out_size; (void)ws_size;
  const float* sent  = (const float*)d_in[0];
  const int*   tags  = (const int*)d_in[1];
  const float* wih1  = (const float*)d_in[2];
  const float* whh1  = (const float*)d_in[3];
  const float* b1    = (const float*)d_in[4];
  const float* wih   = (const float*)d_in[5];
  const float* whh   = (const float*)d_in[6];
  const float* bias  = (const float*)d_in[7];
  const float* fcw   = (const float*)d_in[8];
  const float* fcb   = (const float*)d_in[9];
  const float* h0    = (const float*)d_in[10];
  const float* c0    = (const float*)d_in[11];
  const float* trans = (const float*)d_in[12];
  float* out = (float*)d_out;

  char* ws = (char*)d_ws;
  size_t off = 0;
  auto alloc = [&](size_t bytes) -> void* {
    void* p = ws + off;
    off = (off + bytes + 255) & ~(size_t)255;
    return p;
  };
  u8* whh_f8 = (u8*)alloc((size_t)7 * 2 * 1024 * 256);
  u8* wih_f8 = (u8*)alloc((size_t)6 * 2 * 1024 * 512);
  u8* fcw_f8 = (u8*)alloc((size_t)64 * 512);
  u8* xw     = (u8*)alloc((size_t)16384 * 2048);
  u8* ob[3];
  for (int i = 0; i < 3; ++i) ob[i] = (u8*)alloc((size_t)16384 * 512);
  float* feats = (float*)alloc((size_t)16384 * 64 * 4);

  hipLaunchKernelGGL(pack_kernel, dim3(4096), dim3(256), 0, stream,
                     whh1, whh, wih, fcw, whh_f8, wih_f8, fcw_f8);
  hipLaunchKernelGGL(xw1_kernel, dim3(32768), dim3(256), 0, stream, sent, wih1, b1, xw);
  hipLaunchKernelGGL(scan_kernel, dim3(16), dim3(512), 0, stream,
                     whh_f8, xw, h0, c0, ob[0]);
  for (int L = 1; L < 7; ++L) {
    const u8* curb = ob[(L - 1) % 3];
    const u8* prevb = (L >= 2) ? ob[(L - 2) % 3] : nullptr;
    hipLaunchKernelGGL(gemm_xw_kernel, dim3(8, 256), dim3(256), 0, stream,
                       curb, prevb, wih_f8 + (size_t)(L - 1) * 2 * 1024 * 512,
                       bias + (size_t)(L - 1) * 2048, xw);
    hipLaunchKernelGGL(scan_kernel, dim3(16), dim3(512), 0, stream,
                       whh_f8 + (size_t)L * 2 * 1024 * 256, xw,
                       h0 + (size_t)L * 2 * 128 * 256, c0 + (size_t)L * 2 * 128 * 256,
                       ob[L % 3]);
  }
  hipLaunchKernelGGL(fc_kernel, dim3(256), dim3(256), 0, stream, ob[0], fcw_f8, fcb, feats);
  hipLaunchKernelGGL(crf_kernel, dim3(128), dim3(64), 0, stream, feats, trans, tags, out);
}

// Round 14
// 2211.728 us; speedup vs baseline: 1.2872x; 1.1387x over previous
//
#include <hip/hip_runtime.h>
#include <stdint.h>

#define T_LEN 128
#define BATCH 128
#define DHID 512
#define H 256
#define NTAGS 60
#define START_TAG 58
#define STOP_TAG 59
#define NEGV -10000.0f

typedef __attribute__((ext_vector_type(4))) float floatx4;
typedef __attribute__((ext_vector_type(2))) float floatx2;
typedef __attribute__((ext_vector_type(8))) int v8i;
typedef unsigned short u16;
typedef unsigned char u8;
typedef unsigned int u32;
typedef unsigned long long u64c;

#define SCALE1 0x7F7F7F7F  // E8M0 = 1.0 in every byte

__device__ __forceinline__ u16 f2bf(float f) {
  union { float f; uint32_t u; } c; c.f = f;
  uint32_t u = c.u;
  u += 0x7FFFu + ((u >> 16) & 1u);
  return (u16)(u >> 16);
}
// HW fp8 (e4m3) conversions
__device__ __forceinline__ floatx4 f8x4tof(u32 v) {
  floatx2 lo = __builtin_amdgcn_cvt_pk_f32_fp8((int)v, false);
  floatx2 hi = __builtin_amdgcn_cvt_pk_f32_fp8((int)v, true);
  floatx4 r;
  r[0] = lo[0]; r[1] = lo[1]; r[2] = hi[0]; r[3] = hi[1];
  return r;
}
__device__ __forceinline__ u8 ftof8(float f) {
  return (u8)(__builtin_amdgcn_cvt_pk_fp8_f32(f, f, 0, false) & 0xff);
}
__device__ __forceinline__ u32 pk4f8(float a, float b, float c, float d) {
  int o = __builtin_amdgcn_cvt_pk_fp8_f32(a, b, 0, false);
  o = __builtin_amdgcn_cvt_pk_fp8_f32(c, d, o, true);
  return (u32)o;
}
__device__ __forceinline__ float sigx(float x) {
  float e = __expf(-x);
  return __builtin_amdgcn_rcpf(1.0f + e);
}
__device__ __forceinline__ float tanhx(float x) {
  float e = __expf(-2.0f * x);
  return 2.0f * __builtin_amdgcn_rcpf(1.0f + e) - 1.0f;
}
__device__ __forceinline__ u32 relu8(u32 a) {
  u32 m = (a & 0x80808080u) >> 7;
  m *= 255u;
  return a & ~m;
}
__device__ __forceinline__ u32 reluadd8(u32 a, u32 b) {
  floatx4 av = f8x4tof(relu8(a));
  floatx4 bv = f8x4tof(relu8(b));
  return pk4f8(av[0] + bv[0], av[1] + bv[1], av[2] + bv[2], av[3] + bv[3]);
}
// 32-byte fragment builders
__device__ __forceinline__ v8i frag_lds(const u8* p) {  // 8-B aligned LDS
  union { long l[4]; v8i v; } u;
  u.l[0] = *(const long*)(p);
  u.l[1] = *(const long*)(p + 8);
  u.l[2] = *(const long*)(p + 16);
  u.l[3] = *(const long*)(p + 24);
  return u.v;
}
__device__ __forceinline__ v8i frag_pair(uint4 a, uint4 b) {
  union { uint4 q[2]; v8i v; } u;
  u.q[0] = a; u.q[1] = b;
  return u.v;
}
#define MFMA128(a, b, c) \
  __builtin_amdgcn_mfma_scale_f32_16x16x128_f8f6f4((a), (b), (c), 0, 0, 0, SCALE1, 0, SCALE1)

// ---------------------------------------------------------------------------
// Pack weights -> fp8: whh [7][2][1024][256], wih [6][2][1024][512], fcw [64][512].
// ---------------------------------------------------------------------------
__global__ void pack_kernel(const float* __restrict__ whh1, const float* __restrict__ whh,
                            const float* __restrict__ wih, const float* __restrict__ fcw,
                            u8* __restrict__ whh_f8, u8* __restrict__ wih_f8,
                            u8* __restrict__ fcw_f8) {
  const int n_whh1 = 2 * 1024 * 256;
  const int n_whh  = 6 * 2 * 1024 * 256;
  const int n_wih  = 6 * 2 * 1024 * 512;
  const int n_fcw  = 64 * 512;
  const int total = n_whh1 + n_whh + n_wih + n_fcw;
  for (int i = blockIdx.x * blockDim.x + threadIdx.x; i < total; i += gridDim.x * blockDim.x) {
    if (i < n_whh1) {
      whh_f8[i] = ftof8(whh1[i]);
    } else if (i < n_whh1 + n_whh) {
      whh_f8[i] = ftof8(whh[i - n_whh1]);
    } else if (i < n_whh1 + n_whh + n_wih) {
      int j = i - n_whh1 - n_whh;
      wih_f8[j] = ftof8(wih[j]);
    } else {
      int j = i - n_whh1 - n_whh - n_wih;
      int row = j >> 9;
      fcw_f8[j] = (row < NTAGS) ? ftof8(fcw[j]) : (u8)0;
    }
  }
}

// ---------------------------------------------------------------------------
// Layer-1 xw (Din=3), fp8, layout xw[bc8][t][col(2048)][16 batches].
// ---------------------------------------------------------------------------
__global__ void xw1_kernel(const float* __restrict__ sent, const float* __restrict__ wih1,
                           const float* __restrict__ b1, u8* __restrict__ xw) {
  int u = blockIdx.x * blockDim.x + threadIdx.x;
  int qq = u & 3;
  int col = (u >> 2) & 2047;
  int t = (u >> 13) & 127;
  int bc = u >> 20;
  const float* w = wih1 + col * 3;
  float w0 = w[0], w1 = w[1], w2 = w[2], bv = b1[col];
  float o[4];
#pragma unroll
  for (int j = 0; j < 4; ++j) {
    int b = bc * 16 + qq * 4 + j;
    const float* x = sent + (t * BATCH + b) * 3;
    o[j] = bv + x[0] * w0 + x[1] * w1 + x[2] * w2;
  }
  *(u32*)(xw + (size_t)u * 4) = pk4f8(o[0], o[1], o[2], o[3]);
}

// ---------------------------------------------------------------------------
// xw GEMM layers 2..7 (plain fp8 K=32 MFMA — measured fastest).
// ---------------------------------------------------------------------------
__launch_bounds__(256, 4)
__global__ void gemm_xw_kernel(const u8* __restrict__ cur, const u8* __restrict__ prev,
                               const u8* __restrict__ W, const float* __restrict__ bias,
                               u8* __restrict__ xw) {
  __shared__ __align__(16) u8 As[64][72];
  const int nbase = blockIdx.x * 256;
  const int m0 = blockIdx.y * 64;
  const int tid = threadIdx.x;
  const int wv = tid >> 6, ln = tid & 63;
  const int c16 = ln & 15, q = ln >> 4;
  const int ncol0 = nbase + wv * 64;

  floatx4 acc[4][4];
#pragma unroll
  for (int i = 0; i < 4; ++i)
#pragma unroll
    for (int j = 0; j < 4; ++j) { acc[i][j][0] = 0.f; acc[i][j][1] = 0.f; acc[i][j][2] = 0.f; acc[i][j][3] = 0.f; }

  for (int kc = 0; kc < 8; ++kc) {
    {
      int r = tid >> 2;
      int cb = (tid & 3) * 16;
      size_t g = (size_t)(m0 + r) * DHID + kc * 64 + cb;
      uint4 a4 = *(const uint4*)(cur + g);
      if (prev) {
        uint4 p4 = *(const uint4*)(prev + g);
        a4.x = reluadd8(a4.x, p4.x); a4.y = reluadd8(a4.y, p4.y);
        a4.z = reluadd8(a4.z, p4.z); a4.w = reluadd8(a4.w, p4.w);
      } else {
        a4.x = relu8(a4.x); a4.y = relu8(a4.y);
        a4.z = relu8(a4.z); a4.w = relu8(a4.w);
      }
      u64c lo = ((u64c)a4.y << 32) | a4.x;
      u64c hi = ((u64c)a4.w << 32) | a4.z;
      *(u64c*)(&As[r][cb]) = lo;
      *(u64c*)(&As[r][cb + 8]) = hi;
    }
    __syncthreads();
#pragma unroll
    for (int kt = 0; kt < 2; ++kt) {
      int kg = kc * 64 + kt * 32 + q * 8;
      long bfr[4];
#pragma unroll
      for (int nt = 0; nt < 4; ++nt)
        bfr[nt] = *(const long*)(W + (size_t)(ncol0 + nt * 16 + c16) * DHID + kg);
      long afr[4];
#pragma unroll
      for (int mt = 0; mt < 4; ++mt)
        afr[mt] = *(const long*)(&As[mt * 16 + c16][kt * 32 + q * 8]);
#pragma unroll
      for (int nt = 0; nt < 4; ++nt)
#pragma unroll
        for (int mt = 0; mt < 4; ++mt)
          acc[nt][mt] = __builtin_amdgcn_mfma_f32_16x16x32_fp8_fp8(afr[mt], bfr[nt], acc[nt][mt], 0, 0, 0);
    }
    __syncthreads();
  }
  const int t = m0 >> 7;
  const int bc0 = (m0 & 127) >> 4;
#pragma unroll
  for (int nt = 0; nt < 4; ++nt) {
    int col = ncol0 + nt * 16 + c16;
    float bv = bias[col];
#pragma unroll
    for (int mt = 0; mt < 4; ++mt) {
      u32 o = pk4f8(acc[nt][mt][0] + bv, acc[nt][mt][1] + bv,
                    acc[nt][mt][2] + bv, acc[nt][mt][3] + bv);
      *(u32*)(xw + (((size_t)(bc0 + mt) * T_LEN + t) * 2048 + col) * 16 + q * 4) = o;
    }
  }
}

// ---------------------------------------------------------------------------
// LSTM scan. Grid: 16 (dir*8+bc), block 512 (8 waves).
// A = h (M=batch=c16), B = W. MX-scaled K=128 MFMA.
// ALL FOUR gates' W held in VGPRs (16 v8i = 128 VGPRs/wave), pinned against
// compiler rematerialization with an opaque asm "+v" touch — eliminates both
// the per-step L2 W stream and the Wl LDS array.
// h fp8 double-buffered LDS (8.4 KB total); one barrier/step; obuf fp8 copy.
// ---------------------------------------------------------------------------
__launch_bounds__(512, 1)
__global__ void scan_kernel(const u8* __restrict__ whh, const u8* __restrict__ xw,
                            const float* __restrict__ h0, const float* __restrict__ c0,
                            u8* __restrict__ obuf) {
  __shared__ __align__(16) u8 hbuf[2][16][264];  // 8448 B
  const int bc  = blockIdx.x & 7;
  const int dir = blockIdx.x >> 3;
  const int b0  = bc * 16;
  const int tid = threadIdx.x;
  const int ln = tid & 63;
  const int wv = tid >> 6;
  const int c16 = ln & 15, q = ln >> 4;
  const int col0 = wv * 32;  // wave's 32 h-cols

  // --- ALL gates of W -> VGPR B-fragments [g][st][kc], then pin ---
  v8i wfr[4][2][2];
#pragma unroll
  for (int g = 0; g < 4; ++g)
#pragma unroll
    for (int st = 0; st < 2; ++st)
#pragma unroll
      for (int kc = 0; kc < 2; ++kc) {
        const u8* p4 = whh + ((size_t)dir * 1024 + g * 256 + col0 + st * 16 + c16) * 256 +
                       kc * 128 + q * 32;
        wfr[g][st][kc] = frag_pair(*(const uint4*)p4, *(const uint4*)(p4 + 16));
      }
#pragma unroll
  for (int g = 0; g < 4; ++g)
#pragma unroll
    for (int st = 0; st < 2; ++st)
#pragma unroll
      for (int kc = 0; kc < 2; ++kc)
        asm volatile("" : "+v"(wfr[g][st][kc]));  // opaque def: no rematerialization

  // --- h0 -> hbuf[0] (fp8; rows = batch 0..15) ---
  {
    int row = tid >> 5, cc = (tid & 31) * 8;
    const float* hr = h0 + ((size_t)dir * BATCH + b0 + row) * H + cc;
    *(u32*)(&hbuf[0][row][cc])     = pk4f8(hr[0], hr[1], hr[2], hr[3]);
    *(u32*)(&hbuf[0][row][cc + 4]) = pk4f8(hr[4], hr[5], hr[6], hr[7]);
  }
  // --- c state: batch = q*4+r, col = col0+st*16+c16 ---
  float creg[2][4];
#pragma unroll
  for (int st = 0; st < 2; ++st)
#pragma unroll
    for (int r = 0; r < 4; ++r)
      creg[st][r] = c0[((size_t)dir * BATCH + b0 + q * 4 + r) * H + col0 + st * 16 + c16];
  __syncthreads();

  // xw addressing
  const u8* xwt = xw + ((size_t)bc * T_LEN + (dir ? T_LEN - 1 : 0)) * 2048 * 16;
  const ptrdiff_t xstep = (dir ? -1 : 1) * (ptrdiff_t)(2048 * 16);
  int xoff[4][2];
#pragma unroll
  for (int g = 0; g < 4; ++g)
#pragma unroll
    for (int st = 0; st < 2; ++st)
      xoff[g][st] = (dir * 1024 + g * 256 + col0 + st * 16 + c16) * 16 + q * 4;

  u8* obt = obuf + ((size_t)(dir ? T_LEN - 1 : 0) * BATCH) * DHID;
  const ptrdiff_t ostep = (dir ? -1 : 1) * (ptrdiff_t)(BATCH * DHID);

  // prefetch s=0 xw
  u32 xwn[4][2];
#pragma unroll
  for (int g = 0; g < 4; ++g)
#pragma unroll
    for (int st = 0; st < 2; ++st)
      xwn[g][st] = *(const u32*)(xwt + xoff[g][st]);

  for (int s = 0; s < T_LEN; ++s) {
    const int p = s & 1, pn = p ^ 1;

    // 1) acc init from xw
    floatx4 acc[4][2];
#pragma unroll
    for (int g = 0; g < 4; ++g)
#pragma unroll
      for (int st = 0; st < 2; ++st)
        acc[g][st] = f8x4tof(xwn[g][st]);

    // 2) prefetch next step's xw
    if (s + 1 < T_LEN) {
      const u8* xn = xwt + xstep;
#pragma unroll
      for (int g = 0; g < 4; ++g)
#pragma unroll
        for (int st = 0; st < 2; ++st)
          xwn[g][st] = *(const u32*)(xn + xoff[g][st]);
    }

    // 3) h A-frags (2 K-chunks of 128)
    v8i hfr[2];
#pragma unroll
    for (int kc = 0; kc < 2; ++kc)
      hfr[kc] = frag_lds(&hbuf[p][c16][kc * 128 + q * 32]);

    // 4) MFMA: all W resident in VGPRs
#pragma unroll
    for (int g = 0; g < 4; ++g)
#pragma unroll
      for (int st = 0; st < 2; ++st)
#pragma unroll
        for (int kc = 0; kc < 2; ++kc)
          acc[g][st] = MFMA128(hfr[kc], wfr[g][st][kc], acc[g][st]);

    // 5) gates -> h' (batch = q*4+r, col = col0+st*16+c16)
#pragma unroll
    for (int st = 0; st < 2; ++st)
#pragma unroll
      for (int r = 0; r < 4; ++r) {
        float ig = sigx(acc[0][st][r]);
        float fg = sigx(acc[1][st][r]);
        float gg = tanhx(acc[2][st][r]);
        float og = sigx(acc[3][st][r]);
        float cn = fg * creg[st][r] + ig * gg;
        creg[st][r] = cn;
        hbuf[pn][q * 4 + r][col0 + st * 16 + c16] = ftof8(og * tanhx(cn));
      }
    __syncthreads();

    // 6) obuf copy (fp8, 8B/thread, coalesced)
    {
      int row = tid >> 5, cc = (tid & 31) * 8;
      u64c v = *(const u64c*)(&hbuf[pn][row][cc]);
      *(u64c*)(obt + ((size_t)(b0 + row)) * DHID + dir * H + cc) = v;
    }
    xwt += xstep;
    obt += ostep;
  }
}

// ---------------------------------------------------------------------------
// FC: feats[16384][64] = out7(fp8)[16384][512] @ fcw^T + fc_b  (fp8 MFMA)
// ---------------------------------------------------------------------------
__launch_bounds__(256, 4)
__global__ void fc_kernel(const u8* __restrict__ A, const u8* __restrict__ W,
                          const float* __restrict__ fb, float* __restrict__ feats) {
  const int tid = threadIdx.x, wv = tid >> 6, ln = tid & 63;
  const int c16 = ln & 15, q = ln >> 4;
  const int m0 = blockIdx.x * 64 + wv * 16;
  floatx4 acc[4];
#pragma unroll
  for (int i = 0; i < 4; ++i) { acc[i][0] = 0.f; acc[i][1] = 0.f; acc[i][2] = 0.f; acc[i][3] = 0.f; }
#pragma unroll
  for (int kt = 0; kt < 16; ++kt) {
    long a = *(const long*)(A + (size_t)(m0 + c16) * DHID + kt * 32 + q * 8);
#pragma unroll
    for (int nt = 0; nt < 4; ++nt) {
      long b = *(const long*)(W + (size_t)(nt * 16 + c16) * DHID + kt * 32 + q * 8);
      acc[nt] = __builtin_amdgcn_mfma_f32_16x16x32_fp8_fp8(a, b, acc[nt], 0, 0, 0);
    }
  }
#pragma unroll
  for (int nt = 0; nt < 4; ++nt) {
    int n = nt * 16 + c16;
    if (n < NTAGS) {
      float bv = fb[n];
#pragma unroll
      for (int r = 0; r < 4; ++r)
        feats[(size_t)(m0 + q * 4 + r) * 64 + n] = acc[nt][r] + bv;
    }
  }
}

// ---------------------------------------------------------------------------
// CRF: one wave per batch item.
// ---------------------------------------------------------------------------
__launch_bounds__(64, 1)
__global__ void crf_kernel(const float* __restrict__ feats, const float* __restrict__ trans,
                           const int* __restrict__ tags, float* __restrict__ out) {
  __shared__ float Tl[60][65];
  __shared__ float abuf[2][64];
  const int b = blockIdx.x;
  const int ln = threadIdx.x;
  for (int i = ln; i < 3600; i += 64) Tl[i / 60][i % 60] = trans[i];
  __syncthreads();

  float gsc = 0.f;
  for (int t = ln; t < T_LEN; t += 64) {
    int tg = tags[t * BATCH + b];
    int pv = (t == 0) ? START_TAG : tags[(t - 1) * BATCH + b];
    gsc += Tl[tg][pv] + feats[(size_t)(t * BATCH + b) * 64 + tg];
  }
#pragma unroll
  for (int off = 32; off > 0; off >>= 1) gsc += __shfl_down(gsc, off);
  if (ln == 0) gsc += Tl[STOP_TAG][tags[(T_LEN - 1) * BATCH + b]];

  abuf[0][ln] = (ln == START_TAG) ? 0.f : NEGV;
  __syncthreads();
  const float* Trow = Tl[ln < NTAGS ? ln : 0];
  const int myk = (ln < NTAGS) ? ln : 0;
  for (int t = 0; t < T_LEN; ++t) {
    const int cb = t & 1, nb2 = cb ^ 1;
    float m = -1e30f;
    for (int p = 0; p < NTAGS; ++p) m = fmaxf(m, abuf[cb][p] + Trow[p]);
    float ssum = 0.f;
    for (int p = 0; p < NTAGS; ++p) ssum += __expf(abuf[cb][p] + Trow[p] - m);
    float nv = m + __logf(ssum) + feats[(size_t)(t * BATCH + b) * 64 + myk];
    abuf[nb2][ln] = (ln < NTAGS) ? nv : NEGV;
    __syncthreads();
  }

  float v = (ln < NTAGS) ? (abuf[T_LEN & 1][ln] + Tl[STOP_TAG][ln]) : -1e30f;
  float mm = v;
#pragma unroll
  for (int off = 32; off > 0; off >>= 1) mm = fmaxf(mm, __shfl_down(mm, off));
  mm = __shfl(mm, 0);
  float es = __expf(v - mm);
#pragma unroll
  for (int off = 32; off > 0; off >>= 1) es += __shfl_down(es, off);
  if (ln == 0) out[b] = mm + __logf(es) - gsc;
}

// ---------------------------------------------------------------------------
extern "C" void kernel_launch(void* const* d_in, const int* in_sizes, int n_in,
                              void* d_out, int out_size, void* d_ws, size_t ws_size,
                              hipStream_t stream) {
  (void)in_sizes; (void)n_in; (void)out_size; (void)ws_size;
  const float* sent  = (const float*)d_in[0];
  const int*   tags  = (const int*)d_in[1];
  const float* wih1  = (const float*)d_in[2];
  const float* whh1  = (const float*)d_in[3];
  const float* b1    = (const float*)d_in[4];
  const float* wih   = (const float*)d_in[5];
  const float* whh   = (const float*)d_in[6];
  const float* bias  = (const float*)d_in[7];
  const float* fcw   = (const float*)d_in[8];
  const float* fcb   = (const float*)d_in[9];
  const float* h0    = (const float*)d_in[10];
  const float* c0    = (const float*)d_in[11];
  const float* trans = (const float*)d_in[12];
  float* out = (float*)d_out;

  char* ws = (char*)d_ws;
  size_t off = 0;
  auto alloc = [&](size_t bytes) -> void* {
    void* p = ws + off;
    off = (off + bytes + 255) & ~(size_t)255;
    return p;
  };
  u8* whh_f8 = (u8*)alloc((size_t)7 * 2 * 1024 * 256);
  u8* wih_f8 = (u8*)alloc((size_t)6 * 2 * 1024 * 512);
  u8* fcw_f8 = (u8*)alloc((size_t)64 * 512);
  u8* xw     = (u8*)alloc((size_t)16384 * 2048);
  u8* ob[3];
  for (int i = 0; i < 3; ++i) ob[i] = (u8*)alloc((size_t)16384 * 512);
  float* feats = (float*)alloc((size_t)16384 * 64 * 4);

  hipLaunchKernelGGL(pack_kernel, dim3(4096), dim3(256), 0, stream,
                     whh1, whh, wih, fcw, whh_f8, wih_f8, fcw_f8);
  hipLaunchKernelGGL(xw1_kernel, dim3(32768), dim3(256), 0, stream, sent, wih1, b1, xw);
  hipLaunchKernelGGL(scan_kernel, dim3(16), dim3(512), 0, stream,
                     whh_f8, xw, h0, c0, ob[0]);
  for (int L = 1; L < 7; ++L) {
    const u8* curb = ob[(L - 1) % 3];
    const u8* prevb = (L >= 2) ? ob[(L - 2) % 3] : nullptr;
    hipLaunchKernelGGL(gemm_xw_kernel, dim3(8, 256), dim3(256), 0, stream,
                       curb, prevb, wih_f8 + (size_t)(L - 1) * 2 * 1024 * 512,
                       bias + (size_t)(L - 1) * 2048, xw);
    hipLaunchKernelGGL(scan_kernel, dim3(16), dim3(512), 0, stream,
                       whh_f8 + (size_t)L * 2 * 1024 * 256, xw,
                       h0 + (size_t)L * 2 * 128 * 256, c0 + (size_t)L * 2 * 128 * 256,
                       ob[L % 3]);
  }
  hipLaunchKernelGGL(fc_kernel, dim3(256), dim3(256), 0, stream, ob[0], fcw_f8, fcb, feats);
  hipLaunchKernelGGL(crf_kernel, dim3(128), dim3(64), 0, stream, feats, trans, tags, out);
}

// Round 15
// 2181.376 us; speedup vs baseline: 1.3051x; 1.0139x over previous
//
#include <hip/hip_runtime.h>
#include <stdint.h>

#define T_LEN 128
#define BATCH 128
#define DHID 512
#define H 256
#define NTAGS 60
#define START_TAG 58
#define STOP_TAG 59
#define NEGV -10000.0f

typedef __attribute__((ext_vector_type(4))) float floatx4;
typedef __attribute__((ext_vector_type(2))) float floatx2;
typedef __attribute__((ext_vector_type(8))) int v8i;
typedef unsigned short u16;
typedef unsigned char u8;
typedef unsigned int u32;
typedef unsigned long long u64c;

#define SCALE1 0x7F7F7F7F  // E8M0 = 1.0 in every byte

__device__ __forceinline__ u16 f2bf(float f) {
  union { float f; uint32_t u; } c; c.f = f;
  uint32_t u = c.u;
  u += 0x7FFFu + ((u >> 16) & 1u);
  return (u16)(u >> 16);
}
// HW fp8 (e4m3) conversions
__device__ __forceinline__ floatx4 f8x4tof(u32 v) {
  floatx2 lo = __builtin_amdgcn_cvt_pk_f32_fp8((int)v, false);
  floatx2 hi = __builtin_amdgcn_cvt_pk_f32_fp8((int)v, true);
  floatx4 r;
  r[0] = lo[0]; r[1] = lo[1]; r[2] = hi[0]; r[3] = hi[1];
  return r;
}
__device__ __forceinline__ u8 ftof8(float f) {
  return (u8)(__builtin_amdgcn_cvt_pk_fp8_f32(f, f, 0, false) & 0xff);
}
__device__ __forceinline__ u32 pk4f8(float a, float b, float c, float d) {
  int o = __builtin_amdgcn_cvt_pk_fp8_f32(a, b, 0, false);
  o = __builtin_amdgcn_cvt_pk_fp8_f32(c, d, o, true);
  return (u32)o;
}
__device__ __forceinline__ float sigx(float x) {
  float e = __expf(-x);
  return __builtin_amdgcn_rcpf(1.0f + e);
}
__device__ __forceinline__ float tanhx(float x) {
  float e = __expf(-2.0f * x);
  return 2.0f * __builtin_amdgcn_rcpf(1.0f + e) - 1.0f;
}
__device__ __forceinline__ u32 relu8(u32 a) {
  u32 m = (a & 0x80808080u) >> 7;
  m *= 255u;
  return a & ~m;
}
__device__ __forceinline__ u32 reluadd8(u32 a, u32 b) {
  floatx4 av = f8x4tof(relu8(a));
  floatx4 bv = f8x4tof(relu8(b));
  return pk4f8(av[0] + bv[0], av[1] + bv[1], av[2] + bv[2], av[3] + bv[3]);
}
// 32-byte fragment builders
__device__ __forceinline__ v8i frag_lds(const u8* p) {  // 8-B aligned LDS
  union { long l[4]; v8i v; } u;
  u.l[0] = *(const long*)(p);
  u.l[1] = *(const long*)(p + 8);
  u.l[2] = *(const long*)(p + 16);
  u.l[3] = *(const long*)(p + 24);
  return u.v;
}
__device__ __forceinline__ v8i frag_pair(uint4 a, uint4 b) {
  union { uint4 q[2]; v8i v; } u;
  u.q[0] = a; u.q[1] = b;
  return u.v;
}
#define MFMA128(a, b, c) \
  __builtin_amdgcn_mfma_scale_f32_16x16x128_f8f6f4((a), (b), (c), 0, 0, 0, SCALE1, 0, SCALE1)

// ---------------------------------------------------------------------------
// Pack weights -> fp8: whh [7][2][1024][256], wih [6][2][1024][512], fcw [64][512].
// ---------------------------------------------------------------------------
__global__ void pack_kernel(const float* __restrict__ whh1, const float* __restrict__ whh,
                            const float* __restrict__ wih, const float* __restrict__ fcw,
                            u8* __restrict__ whh_f8, u8* __restrict__ wih_f8,
                            u8* __restrict__ fcw_f8) {
  const int n_whh1 = 2 * 1024 * 256;
  const int n_whh  = 6 * 2 * 1024 * 256;
  const int n_wih  = 6 * 2 * 1024 * 512;
  const int n_fcw  = 64 * 512;
  const int total = n_whh1 + n_whh + n_wih + n_fcw;
  for (int i = blockIdx.x * blockDim.x + threadIdx.x; i < total; i += gridDim.x * blockDim.x) {
    if (i < n_whh1) {
      whh_f8[i] = ftof8(whh1[i]);
    } else if (i < n_whh1 + n_whh) {
      whh_f8[i] = ftof8(whh[i - n_whh1]);
    } else if (i < n_whh1 + n_whh + n_wih) {
      int j = i - n_whh1 - n_whh;
      wih_f8[j] = ftof8(wih[j]);
    } else {
      int j = i - n_whh1 - n_whh - n_wih;
      int row = j >> 9;
      fcw_f8[j] = (row < NTAGS) ? ftof8(fcw[j]) : (u8)0;
    }
  }
}

// ---------------------------------------------------------------------------
// Layer-1 xw (Din=3), fp8, layout xw[bc8][t][col(2048)][16 batches].
// ---------------------------------------------------------------------------
__global__ void xw1_kernel(const float* __restrict__ sent, const float* __restrict__ wih1,
                           const float* __restrict__ b1, u8* __restrict__ xw) {
  int u = blockIdx.x * blockDim.x + threadIdx.x;
  int qq = u & 3;
  int col = (u >> 2) & 2047;
  int t = (u >> 13) & 127;
  int bc = u >> 20;
  const float* w = wih1 + col * 3;
  float w0 = w[0], w1 = w[1], w2 = w[2], bv = b1[col];
  float o[4];
#pragma unroll
  for (int j = 0; j < 4; ++j) {
    int b = bc * 16 + qq * 4 + j;
    const float* x = sent + (t * BATCH + b) * 3;
    o[j] = bv + x[0] * w0 + x[1] * w1 + x[2] * w2;
  }
  *(u32*)(xw + (size_t)u * 4) = pk4f8(o[0], o[1], o[2], o[3]);
}

// ---------------------------------------------------------------------------
// xw GEMM layers 2..7 (plain fp8 K=32 MFMA — measured fastest).
// ---------------------------------------------------------------------------
__launch_bounds__(256, 4)
__global__ void gemm_xw_kernel(const u8* __restrict__ cur, const u8* __restrict__ prev,
                               const u8* __restrict__ W, const float* __restrict__ bias,
                               u8* __restrict__ xw) {
  __shared__ __align__(16) u8 As[64][72];
  const int nbase = blockIdx.x * 256;
  const int m0 = blockIdx.y * 64;
  const int tid = threadIdx.x;
  const int wv = tid >> 6, ln = tid & 63;
  const int c16 = ln & 15, q = ln >> 4;
  const int ncol0 = nbase + wv * 64;

  floatx4 acc[4][4];
#pragma unroll
  for (int i = 0; i < 4; ++i)
#pragma unroll
    for (int j = 0; j < 4; ++j) { acc[i][j][0] = 0.f; acc[i][j][1] = 0.f; acc[i][j][2] = 0.f; acc[i][j][3] = 0.f; }

  for (int kc = 0; kc < 8; ++kc) {
    {
      int r = tid >> 2;
      int cb = (tid & 3) * 16;
      size_t g = (size_t)(m0 + r) * DHID + kc * 64 + cb;
      uint4 a4 = *(const uint4*)(cur + g);
      if (prev) {
        uint4 p4 = *(const uint4*)(prev + g);
        a4.x = reluadd8(a4.x, p4.x); a4.y = reluadd8(a4.y, p4.y);
        a4.z = reluadd8(a4.z, p4.z); a4.w = reluadd8(a4.w, p4.w);
      } else {
        a4.x = relu8(a4.x); a4.y = relu8(a4.y);
        a4.z = relu8(a4.z); a4.w = relu8(a4.w);
      }
      u64c lo = ((u64c)a4.y << 32) | a4.x;
      u64c hi = ((u64c)a4.w << 32) | a4.z;
      *(u64c*)(&As[r][cb]) = lo;
      *(u64c*)(&As[r][cb + 8]) = hi;
    }
    __syncthreads();
#pragma unroll
    for (int kt = 0; kt < 2; ++kt) {
      int kg = kc * 64 + kt * 32 + q * 8;
      long bfr[4];
#pragma unroll
      for (int nt = 0; nt < 4; ++nt)
        bfr[nt] = *(const long*)(W + (size_t)(ncol0 + nt * 16 + c16) * DHID + kg);
      long afr[4];
#pragma unroll
      for (int mt = 0; mt < 4; ++mt)
        afr[mt] = *(const long*)(&As[mt * 16 + c16][kt * 32 + q * 8]);
#pragma unroll
      for (int nt = 0; nt < 4; ++nt)
#pragma unroll
        for (int mt = 0; mt < 4; ++mt)
          acc[nt][mt] = __builtin_amdgcn_mfma_f32_16x16x32_fp8_fp8(afr[mt], bfr[nt], acc[nt][mt], 0, 0, 0);
    }
    __syncthreads();
  }
  const int t = m0 >> 7;
  const int bc0 = (m0 & 127) >> 4;
#pragma unroll
  for (int nt = 0; nt < 4; ++nt) {
    int col = ncol0 + nt * 16 + c16;
    float bv = bias[col];
#pragma unroll
    for (int mt = 0; mt < 4; ++mt) {
      u32 o = pk4f8(acc[nt][mt][0] + bv, acc[nt][mt][1] + bv,
                    acc[nt][mt][2] + bv, acc[nt][mt][3] + bv);
      *(u32*)(xw + (((size_t)(bc0 + mt) * T_LEN + t) * 2048 + col) * 16 + q * 4) = o;
    }
  }
}

// ---------------------------------------------------------------------------
// LSTM scan. Grid: 16 (dir*8+bc), block 1024 (16 waves -> 4 waves/SIMD).
// Wave w owns 16 h-cols (col0 = w*16), all 4 gates. A = h (M=batch=c16),
// B = W. MX-scaled K=128 MFMA (8 per wave per step).
// W fragments (8 v8i = 64 regs/wave) pinned via opaque asm (R14: compiler
// places them in AGPRs -> resident, zero per-step W traffic).
// h fp8 double-buffered LDS; ONE barrier/step; obuf fp8 copy (tid<512).
// 2x waves/SIMD vs R14 to hide trans/LDS latency (the measured ~1500cyc slack).
// ---------------------------------------------------------------------------
__launch_bounds__(1024, 1)
__global__ void scan_kernel(const u8* __restrict__ whh, const u8* __restrict__ xw,
                            const float* __restrict__ h0, const float* __restrict__ c0,
                            u8* __restrict__ obuf) {
  __shared__ __align__(16) u8 hbuf[2][16][264];  // 8448 B
  const int bc  = blockIdx.x & 7;
  const int dir = blockIdx.x >> 3;
  const int b0  = bc * 16;
  const int tid = threadIdx.x;
  const int ln = tid & 63;
  const int wv = tid >> 6;              // 0..15
  const int c16 = ln & 15, q = ln >> 4;
  const int col0 = wv * 16;             // wave's 16 h-cols

  // --- all 4 gates of W -> VGPR/AGPR B-fragments [g][kc], then pin ---
  v8i wfr[4][2];
#pragma unroll
  for (int g = 0; g < 4; ++g)
#pragma unroll
    for (int kc = 0; kc < 2; ++kc) {
      const u8* p4 = whh + ((size_t)dir * 1024 + g * 256 + col0 + c16) * 256 + kc * 128 + q * 32;
      wfr[g][kc] = frag_pair(*(const uint4*)p4, *(const uint4*)(p4 + 16));
    }
#pragma unroll
  for (int g = 0; g < 4; ++g)
#pragma unroll
    for (int kc = 0; kc < 2; ++kc)
      asm volatile("" : "+v"(wfr[g][kc]));  // opaque def: no rematerialization

  // --- h0 -> hbuf[0] (fp8; rows = batch 0..15; 4B per thread) ---
  {
    int row = tid >> 6;             // 0..15
    int cc = (tid & 63) * 4;        // 0..252
    const float* hr = h0 + ((size_t)dir * BATCH + b0 + row) * H + cc;
    *(u32*)(&hbuf[0][row][cc]) = pk4f8(hr[0], hr[1], hr[2], hr[3]);
  }
  // --- c state: batch = q*4+r, col = col0+c16 ---
  float creg[4];
#pragma unroll
  for (int r = 0; r < 4; ++r)
    creg[r] = c0[((size_t)dir * BATCH + b0 + q * 4 + r) * H + col0 + c16];
  __syncthreads();

  // xw addressing
  const u8* xwt = xw + ((size_t)bc * T_LEN + (dir ? T_LEN - 1 : 0)) * 2048 * 16;
  const ptrdiff_t xstep = (dir ? -1 : 1) * (ptrdiff_t)(2048 * 16);
  int xoff[4];
#pragma unroll
  for (int g = 0; g < 4; ++g)
    xoff[g] = (dir * 1024 + g * 256 + col0 + c16) * 16 + q * 4;

  u8* obt = obuf + ((size_t)(dir ? T_LEN - 1 : 0) * BATCH) * DHID;
  const ptrdiff_t ostep = (dir ? -1 : 1) * (ptrdiff_t)(BATCH * DHID);

  // prefetch s=0 xw
  u32 xwn[4];
#pragma unroll
  for (int g = 0; g < 4; ++g)
    xwn[g] = *(const u32*)(xwt + xoff[g]);

  for (int s = 0; s < T_LEN; ++s) {
    const int p = s & 1, pn = p ^ 1;

    // 1) acc init from xw
    floatx4 acc[4];
#pragma unroll
    for (int g = 0; g < 4; ++g) acc[g] = f8x4tof(xwn[g]);

    // 2) prefetch next step's xw
    if (s + 1 < T_LEN) {
      const u8* xn = xwt + xstep;
#pragma unroll
      for (int g = 0; g < 4; ++g)
        xwn[g] = *(const u32*)(xn + xoff[g]);
    }

    // 3) h A-frags (2 K-chunks of 128)
    v8i hfr[2];
#pragma unroll
    for (int kc = 0; kc < 2; ++kc)
      hfr[kc] = frag_lds(&hbuf[p][c16][kc * 128 + q * 32]);

    // 4) MFMA: all W resident
#pragma unroll
    for (int g = 0; g < 4; ++g)
#pragma unroll
      for (int kc = 0; kc < 2; ++kc)
        acc[g] = MFMA128(hfr[kc], wfr[g][kc], acc[g]);

    // 5) gates -> h' (batch = q*4+r, col = col0+c16)
#pragma unroll
    for (int r = 0; r < 4; ++r) {
      float ig = sigx(acc[0][r]);
      float fg = sigx(acc[1][r]);
      float gg = tanhx(acc[2][r]);
      float og = sigx(acc[3][r]);
      float cn = fg * creg[r] + ig * gg;
      creg[r] = cn;
      hbuf[pn][q * 4 + r][col0 + c16] = ftof8(og * tanhx(cn));
    }
    __syncthreads();

    // 6) obuf copy (fp8, 8B/thread, first 512 threads)
    if (tid < 512) {
      int row = tid >> 5, cc = (tid & 31) * 8;
      u64c v = *(const u64c*)(&hbuf[pn][row][cc]);
      *(u64c*)(obt + ((size_t)(b0 + row)) * DHID + dir * H + cc) = v;
    }
    xwt += xstep;
    obt += ostep;
  }
}

// ---------------------------------------------------------------------------
// FC: feats[16384][64] = out7(fp8)[16384][512] @ fcw^T + fc_b  (fp8 MFMA)
// ---------------------------------------------------------------------------
__launch_bounds__(256, 4)
__global__ void fc_kernel(const u8* __restrict__ A, const u8* __restrict__ W,
                          const float* __restrict__ fb, float* __restrict__ feats) {
  const int tid = threadIdx.x, wv = tid >> 6, ln = tid & 63;
  const int c16 = ln & 15, q = ln >> 4;
  const int m0 = blockIdx.x * 64 + wv * 16;
  floatx4 acc[4];
#pragma unroll
  for (int i = 0; i < 4; ++i) { acc[i][0] = 0.f; acc[i][1] = 0.f; acc[i][2] = 0.f; acc[i][3] = 0.f; }
#pragma unroll
  for (int kt = 0; kt < 16; ++kt) {
    long a = *(const long*)(A + (size_t)(m0 + c16) * DHID + kt * 32 + q * 8);
#pragma unroll
    for (int nt = 0; nt < 4; ++nt) {
      long b = *(const long*)(W + (size_t)(nt * 16 + c16) * DHID + kt * 32 + q * 8);
      acc[nt] = __builtin_amdgcn_mfma_f32_16x16x32_fp8_fp8(a, b, acc[nt], 0, 0, 0);
    }
  }
#pragma unroll
  for (int nt = 0; nt < 4; ++nt) {
    int n = nt * 16 + c16;
    if (n < NTAGS) {
      float bv = fb[n];
#pragma unroll
      for (int r = 0; r < 4; ++r)
        feats[(size_t)(m0 + q * 4 + r) * 64 + n] = acc[nt][r] + bv;
    }
  }
}

// ---------------------------------------------------------------------------
// CRF: one wave per batch item.
// ---------------------------------------------------------------------------
__launch_bounds__(64, 1)
__global__ void crf_kernel(const float* __restrict__ feats, const float* __restrict__ trans,
                           const int* __restrict__ tags, float* __restrict__ out) {
  __shared__ float Tl[60][65];
  __shared__ float abuf[2][64];
  const int b = blockIdx.x;
  const int ln = threadIdx.x;
  for (int i = ln; i < 3600; i += 64) Tl[i / 60][i % 60] = trans[i];
  __syncthreads();

  float gsc = 0.f;
  for (int t = ln; t < T_LEN; t += 64) {
    int tg = tags[t * BATCH + b];
    int pv = (t == 0) ? START_TAG : tags[(t - 1) * BATCH + b];
    gsc += Tl[tg][pv] + feats[(size_t)(t * BATCH + b) * 64 + tg];
  }
#pragma unroll
  for (int off = 32; off > 0; off >>= 1) gsc += __shfl_down(gsc, off);
  if (ln == 0) gsc += Tl[STOP_TAG][tags[(T_LEN - 1) * BATCH + b]];

  abuf[0][ln] = (ln == START_TAG) ? 0.f : NEGV;
  __syncthreads();
  const float* Trow = Tl[ln < NTAGS ? ln : 0];
  const int myk = (ln < NTAGS) ? ln : 0;
  for (int t = 0; t < T_LEN; ++t) {
    const int cb = t & 1, nb2 = cb ^ 1;
    float m = -1e30f;
    for (int p = 0; p < NTAGS; ++p) m = fmaxf(m, abuf[cb][p] + Trow[p]);
    float ssum = 0.f;
    for (int p = 0; p < NTAGS; ++p) ssum += __expf(abuf[cb][p] + Trow[p] - m);
    float nv = m + __logf(ssum) + feats[(size_t)(t * BATCH + b) * 64 + myk];
    abuf[nb2][ln] = (ln < NTAGS) ? nv : NEGV;
    __syncthreads();
  }

  float v = (ln < NTAGS) ? (abuf[T_LEN & 1][ln] + Tl[STOP_TAG][ln]) : -1e30f;
  float mm = v;
#pragma unroll
  for (int off = 32; off > 0; off >>= 1) mm = fmaxf(mm, __shfl_down(mm, off));
  mm = __shfl(mm, 0);
  float es = __expf(v - mm);
#pragma unroll
  for (int off = 32; off > 0; off >>= 1) es += __shfl_down(es, off);
  if (ln == 0) out[b] = mm + __logf(es) - gsc;
}

// ---------------------------------------------------------------------------
extern "C" void kernel_launch(void* const* d_in, const int* in_sizes, int n_in,
                              void* d_out, int out_size, void* d_ws, size_t ws_size,
                              hipStream_t stream) {
  (void)in_sizes; (void)n_in; (void)out_size; (void)ws_size;
  const float* sent  = (const float*)d_in[0];
  const int*   tags  = (const int*)d_in[1];
  const float* wih1  = (const float*)d_in[2];
  const float* whh1  = (const float*)d_in[3];
  const float* b1    = (const float*)d_in[4];
  const float* wih   = (const float*)d_in[5];
  const float* whh   = (const float*)d_in[6];
  const float* bias  = (const float*)d_in[7];
  const float* fcw   = (const float*)d_in[8];
  const float* fcb   = (const float*)d_in[9];
  const float* h0    = (const float*)d_in[10];
  const float* c0    = (const float*)d_in[11];
  const float* trans = (const float*)d_in[12];
  float* out = (float*)d_out;

  char* ws = (char*)d_ws;
  size_t off = 0;
  auto alloc = [&](size_t bytes) -> void* {
    void* p = ws + off;
    off = (off + bytes + 255) & ~(size_t)255;
    return p;
  };
  u8* whh_f8 = (u8*)alloc((size_t)7 * 2 * 1024 * 256);
  u8* wih_f8 = (u8*)alloc((size_t)6 * 2 * 1024 * 512);
  u8* fcw_f8 = (u8*)alloc((size_t)64 * 512);
  u8* xw     = (u8*)alloc((size_t)16384 * 2048);
  u8* ob[3];
  for (int i = 0; i < 3; ++i) ob[i] = (u8*)alloc((size_t)16384 * 512);
  float* feats = (float*)alloc((size_t)16384 * 64 * 4);

  hipLaunchKernelGGL(pack_kernel, dim3(4096), dim3(256), 0, stream,
                     whh1, whh, wih, fcw, whh_f8, wih_f8, fcw_f8);
  hipLaunchKernelGGL(xw1_kernel, dim3(32768), dim3(256), 0, stream, sent, wih1, b1, xw);
  hipLaunchKernelGGL(scan_kernel, dim3(16), dim3(1024), 0, stream,
                     whh_f8, xw, h0, c0, ob[0]);
  for (int L = 1; L < 7; ++L) {
    const u8* curb = ob[(L - 1) % 3];
    const u8* prevb = (L >= 2) ? ob[(L - 2) % 3] : nullptr;
    hipLaunchKernelGGL(gemm_xw_kernel, dim3(8, 256), dim3(256), 0, stream,
                       curb, prevb, wih_f8 + (size_t)(L - 1) * 2 * 1024 * 512,
                       bias + (size_t)(L - 1) * 2048, xw);
    hipLaunchKernelGGL(scan_kernel, dim3(16), dim3(1024), 0, stream,
                       whh_f8 + (size_t)L * 2 * 1024 * 256, xw,
                       h0 + (size_t)L * 2 * 128 * 256, c0 + (size_t)L * 2 * 128 * 256,
                       ob[L % 3]);
  }
  hipLaunchKernelGGL(fc_kernel, dim3(256), dim3(256), 0, stream, ob[0], fcw_f8, fcb, feats);
  hipLaunchKernelGGL(crf_kernel, dim3(128), dim3(64), 0, stream, feats, trans, tags, out);
}